// Round 4
// baseline (281.613 us; speedup 1.0000x reference)
//
#include <hip/hip_runtime.h>
#include <math.h>

// B=16 rows, D=2^21 fp32/row. loss = mean_i sqrt(sum_j (out-lab)^2).
// R3 finding: compiler allocated 32 VGPRs and re-serialized the 8-deep load
// batch (MLP~2/wave, each wave lives ~30us, delivered BW 2.7 TB/s).
// This round: 2-stage software pipeline (groups A/B, unroll-by-2) so batch
// k+1's 8 loads are structurally in flight while batch k is consumed.
// Expect VGPR ~80-96 (verification that the forcing worked).

constexpr int B = 16;
constexpr int D = 2097152;                        // 2^21 floats per row
constexpr int THREADS = 256;
constexpr int GROUP = 4;                          // float4s per stream per batch
constexpr int NBATCH = 8;                         // batches per thread
// per thread: 32 float4 per input stream = 128 floats
constexpr int FLOATS_PER_BLOCK = THREADS * GROUP * NBATCH * 4;   // 32768
constexpr int BLOCKS_PER_ROW = D / FLOATS_PER_BLOCK;             // 64
constexpr int GRID = B * BLOCKS_PER_ROW;                         // 1024

__global__ __launch_bounds__(THREADS)
void sqdiff_partial_kernel(const float4* __restrict__ out,
                           const float4* __restrict__ lab,
                           float* __restrict__ partials) {
    const int row   = blockIdx.x / BLOCKS_PER_ROW;
    const int chunk = blockIdx.x % BLOCKS_PER_ROW;
    const size_t base = (size_t)row * (D / 4)
                      + (size_t)chunk * (THREADS * GROUP * NBATCH)
                      + threadIdx.x;

    float4 oa[GROUP], la[GROUP], ob[GROUP], lb[GROUP];
    float acc0 = 0.0f, acc1 = 0.0f, acc2 = 0.0f, acc3 = 0.0f;

    // prologue: issue batch 0 into group A
#pragma unroll
    for (int i = 0; i < GROUP; ++i)
        oa[i] = out[base + (size_t)i * THREADS];
#pragma unroll
    for (int i = 0; i < GROUP; ++i)
        la[i] = lab[base + (size_t)i * THREADS];

#pragma unroll
    for (int k = 0; k < NBATCH; k += 2) {
        // issue batch k+1 into group B (before consuming A)
        if (k + 1 < NBATCH) {
#pragma unroll
            for (int i = 0; i < GROUP; ++i)
                ob[i] = out[base + (size_t)((k + 1) * GROUP + i) * THREADS];
#pragma unroll
            for (int i = 0; i < GROUP; ++i)
                lb[i] = lab[base + (size_t)((k + 1) * GROUP + i) * THREADS];
        }
        // consume batch k (group A)
#pragma unroll
        for (int i = 0; i < GROUP; ++i) {
            const float dx = oa[i].x - la[i].x;
            const float dy = oa[i].y - la[i].y;
            const float dz = oa[i].z - la[i].z;
            const float dw = oa[i].w - la[i].w;
            acc0 = fmaf(dx, dx, acc0);
            acc1 = fmaf(dy, dy, acc1);
            acc2 = fmaf(dz, dz, acc2);
            acc3 = fmaf(dw, dw, acc3);
        }
        // issue batch k+2 into group A (before consuming B)
        if (k + 2 < NBATCH) {
#pragma unroll
            for (int i = 0; i < GROUP; ++i)
                oa[i] = out[base + (size_t)((k + 2) * GROUP + i) * THREADS];
#pragma unroll
            for (int i = 0; i < GROUP; ++i)
                la[i] = lab[base + (size_t)((k + 2) * GROUP + i) * THREADS];
        }
        // consume batch k+1 (group B)
        if (k + 1 < NBATCH) {
#pragma unroll
            for (int i = 0; i < GROUP; ++i) {
                const float dx = ob[i].x - lb[i].x;
                const float dy = ob[i].y - lb[i].y;
                const float dz = ob[i].z - lb[i].z;
                const float dw = ob[i].w - lb[i].w;
                acc0 = fmaf(dx, dx, acc0);
                acc1 = fmaf(dy, dy, acc1);
                acc2 = fmaf(dz, dz, acc2);
                acc3 = fmaf(dw, dw, acc3);
            }
        }
    }

    float acc = (acc0 + acc1) + (acc2 + acc3);

#pragma unroll
    for (int off = 32; off > 0; off >>= 1)
        acc += __shfl_down(acc, off, 64);

    __shared__ float smem[THREADS / 64];
    const int lane = threadIdx.x & 63;
    const int wave = threadIdx.x >> 6;
    if (lane == 0) smem[wave] = acc;
    __syncthreads();

    if (threadIdx.x == 0)
        partials[blockIdx.x] = smem[0] + smem[1] + smem[2] + smem[3];
}

// One block, 1024 threads = 16 waves. Wave w reduces row w's 64 partials.
__global__ __launch_bounds__(1024)
void finalize_kernel(const float* __restrict__ partials,
                     float* __restrict__ loss) {
    const int wave = threadIdx.x >> 6;   // row
    const int lane = threadIdx.x & 63;

    float s = partials[wave * BLOCKS_PER_ROW + lane];   // 64 partials/row, 1 per lane

#pragma unroll
    for (int off = 32; off > 0; off >>= 1)
        s += __shfl_down(s, off, 64);

    __shared__ float row_dist[B];
    if (lane == 0) row_dist[wave] = sqrtf(s);
    __syncthreads();

    if (wave == 0) {
        float v = (lane < B) ? row_dist[lane] : 0.0f;
#pragma unroll
        for (int off = 32; off > 0; off >>= 1)
            v += __shfl_down(v, off, 64);
        if (lane == 0) loss[0] = v * (1.0f / (float)B);
    }
}

extern "C" void kernel_launch(void* const* d_in, const int* in_sizes, int n_in,
                              void* d_out, int out_size, void* d_ws, size_t ws_size,
                              hipStream_t stream) {
    const float4* out_p = (const float4*)d_in[0];
    const float4* lab_p = (const float4*)d_in[1];
    float* partials = (float*)d_ws;   // 1024 floats, fully overwritten

    sqdiff_partial_kernel<<<GRID, THREADS, 0, stream>>>(out_p, lab_p, partials);
    finalize_kernel<<<1, 1024, 0, stream>>>(partials, (float*)d_out);
}

// Round 5
// 276.549 us; speedup vs baseline: 1.0183x; 1.0183x over previous
//
#include <hip/hip_runtime.h>
#include <math.h>

// B=16 rows, D=2^21 fp32/row. loss = mean_i sqrt(sum_j (out-lab)^2).
// R4 finding: compiler collapsed the A/B pipeline again (VGPR=40, MLP~2/wave,
// dur invariant at ~101us, delivered 2.65 TB/s = 4.4 B/cyc/CU).
// R5: force the pipeline with __builtin_amdgcn_sched_barrier(0) fences +
// __launch_bounds__(256,2) register budget. Discriminates:
//   (a) compiler-serialization theory -> dur <= 55us
//   (b) per-CU outstanding-miss cap   -> dur unchanged  => R6: global_load_lds

constexpr int B = 16;
constexpr int D = 2097152;                        // 2^21 floats per row
constexpr int THREADS = 256;
constexpr int GROUP = 4;                          // float4s per stream per batch
constexpr int NBATCH = 8;                         // batches per thread
constexpr int FLOATS_PER_BLOCK = THREADS * GROUP * NBATCH * 4;   // 32768 per stream
constexpr int BLOCKS_PER_ROW = D / FLOATS_PER_BLOCK;             // 64
constexpr int GRID = B * BLOCKS_PER_ROW;                         // 1024

__global__ __launch_bounds__(THREADS, 2)          // allow up to 128 VGPRs
void sqdiff_partial_kernel(const float4* __restrict__ out,
                           const float4* __restrict__ lab,
                           float* __restrict__ partials) {
    const int row   = blockIdx.x / BLOCKS_PER_ROW;
    const int chunk = blockIdx.x % BLOCKS_PER_ROW;
    const size_t base = (size_t)row * (D / 4)
                      + (size_t)chunk * (THREADS * GROUP * NBATCH)
                      + threadIdx.x;

    float4 oa[GROUP], la[GROUP], ob[GROUP], lb[GROUP];
    float acc0 = 0.0f, acc1 = 0.0f, acc2 = 0.0f, acc3 = 0.0f;

    // prologue: batch 0 -> group A
#pragma unroll
    for (int i = 0; i < GROUP; ++i)
        oa[i] = out[base + (size_t)i * THREADS];
#pragma unroll
    for (int i = 0; i < GROUP; ++i)
        la[i] = lab[base + (size_t)i * THREADS];

#pragma unroll
    for (int k = 0; k < NBATCH; k += 2) {
        // issue batch k+1 -> group B
        if (k + 1 < NBATCH) {
#pragma unroll
            for (int i = 0; i < GROUP; ++i)
                ob[i] = out[base + (size_t)((k + 1) * GROUP + i) * THREADS];
#pragma unroll
            for (int i = 0; i < GROUP; ++i)
                lb[i] = lab[base + (size_t)((k + 1) * GROUP + i) * THREADS];
        }
        // fence: compute below may not move above; loads above may not sink below
        __builtin_amdgcn_sched_barrier(0);
        // consume batch k (group A)
#pragma unroll
        for (int i = 0; i < GROUP; ++i) {
            const float dx = oa[i].x - la[i].x;
            const float dy = oa[i].y - la[i].y;
            const float dz = oa[i].z - la[i].z;
            const float dw = oa[i].w - la[i].w;
            acc0 = fmaf(dx, dx, acc0);
            acc1 = fmaf(dy, dy, acc1);
            acc2 = fmaf(dz, dz, acc2);
            acc3 = fmaf(dw, dw, acc3);
        }
        // issue batch k+2 -> group A
        if (k + 2 < NBATCH) {
#pragma unroll
            for (int i = 0; i < GROUP; ++i)
                oa[i] = out[base + (size_t)((k + 2) * GROUP + i) * THREADS];
#pragma unroll
            for (int i = 0; i < GROUP; ++i)
                la[i] = lab[base + (size_t)((k + 2) * GROUP + i) * THREADS];
        }
        __builtin_amdgcn_sched_barrier(0);
        // consume batch k+1 (group B)
        if (k + 1 < NBATCH) {
#pragma unroll
            for (int i = 0; i < GROUP; ++i) {
                const float dx = ob[i].x - lb[i].x;
                const float dy = ob[i].y - lb[i].y;
                const float dz = ob[i].z - lb[i].z;
                const float dw = ob[i].w - lb[i].w;
                acc0 = fmaf(dx, dx, acc0);
                acc1 = fmaf(dy, dy, acc1);
                acc2 = fmaf(dz, dz, acc2);
                acc3 = fmaf(dw, dw, acc3);
            }
        }
    }

    float acc = (acc0 + acc1) + (acc2 + acc3);

#pragma unroll
    for (int off = 32; off > 0; off >>= 1)
        acc += __shfl_down(acc, off, 64);

    __shared__ float smem[THREADS / 64];
    const int lane = threadIdx.x & 63;
    const int wave = threadIdx.x >> 6;
    if (lane == 0) smem[wave] = acc;
    __syncthreads();

    if (threadIdx.x == 0)
        partials[blockIdx.x] = smem[0] + smem[1] + smem[2] + smem[3];
}

// One block, 1024 threads = 16 waves. Wave w reduces row w's 64 partials.
__global__ __launch_bounds__(1024)
void finalize_kernel(const float* __restrict__ partials,
                     float* __restrict__ loss) {
    const int wave = threadIdx.x >> 6;   // row
    const int lane = threadIdx.x & 63;

    float s = partials[wave * BLOCKS_PER_ROW + lane];

#pragma unroll
    for (int off = 32; off > 0; off >>= 1)
        s += __shfl_down(s, off, 64);

    __shared__ float row_dist[B];
    if (lane == 0) row_dist[wave] = sqrtf(s);
    __syncthreads();

    if (wave == 0) {
        float v = (lane < B) ? row_dist[lane] : 0.0f;
#pragma unroll
        for (int off = 32; off > 0; off >>= 1)
            v += __shfl_down(v, off, 64);
        if (lane == 0) loss[0] = v * (1.0f / (float)B);
    }
}

extern "C" void kernel_launch(void* const* d_in, const int* in_sizes, int n_in,
                              void* d_out, int out_size, void* d_ws, size_t ws_size,
                              hipStream_t stream) {
    const float4* out_p = (const float4*)d_in[0];
    const float4* lab_p = (const float4*)d_in[1];
    float* partials = (float*)d_ws;   // 1024 floats, fully overwritten

    sqdiff_partial_kernel<<<GRID, THREADS, 0, stream>>>(out_p, lab_p, partials);
    finalize_kernel<<<1, 1024, 0, stream>>>(partials, (float*)d_out);
}